// Round 1
// baseline (256.421 us; speedup 1.0000x reference)
//
#include <hip/hip_runtime.h>

// CNN encoder as implicit-im2col GEMM:
//   A(M=32*2040, K=1024) x Wp(K=1024, N=256), Wp[fd][k] = filt[fd]*W_k[fd][k]
//   out = relu(A*Wp + b_k)
// A row l = contiguous user_batch[b, l*128 : l*128+1024]  (sliding window)

#define L_SZ   2048
#define NWIN   2040   // L - F  (reference uses L - F, not L - F + 1)
#define BM     128
#define MT     16     // ceil(2040/128)

typedef __attribute__((ext_vector_type(8))) short bf16x8;
typedef __attribute__((ext_vector_type(4))) short bf16x4;
typedef __attribute__((ext_vector_type(4))) float f32x4;

static __device__ __forceinline__ short f2bf(float f) {
    union { float f; unsigned u; } v; v.f = f;
    unsigned r = v.u + 0x7FFFu + ((v.u >> 16) & 1u);
    return (short)(r >> 16);
}

__global__ __launch_bounds__(256) void cnn_enc_kernel(
    const float* __restrict__ ub, const float* __restrict__ filt,
    const float* __restrict__ Wk, const float* __restrict__ bk,
    float* __restrict__ out)
{
    // A slab: 135 rows x 128 d, bf16, row stride 136 (+16B pad -> 2-way reads)
    __shared__ short sA[135 * 136];
    // W chunk: 128 n x 64 k, bf16, transposed [n][k], XOR chunk swizzle
    __shared__ short sW[128 * 64];

    const int tid   = threadIdx.x;
    const int bid   = blockIdx.x;
    const int nt    = bid & 1;          // N-tile (0/1)
    const int mt    = (bid >> 1) & 15;  // M-tile
    const int batch = bid >> 5;         // 0..31
    const int l0    = mt * BM;

    // ---- stage A slab once: rows l0..l0+134 (row index clamped in-bounds;
    //      clamped rows only feed masked-out outputs), fp32 -> bf16
    for (int idx = tid; idx < 135 * 32; idx += 256) {
        int r  = idx >> 5;
        int dc = idx & 31;
        int rg = l0 + r; if (rg > L_SZ - 1) rg = L_SZ - 1;
        const float4 v = *reinterpret_cast<const float4*>(
            ub + (((size_t)batch * L_SZ + rg) << 7) + (dc << 2));
        bf16x4 o;
        o.x = f2bf(v.x); o.y = f2bf(v.y); o.z = f2bf(v.z); o.w = f2bf(v.w);
        *reinterpret_cast<bf16x4*>(&sA[r * 136 + (dc << 2)]) = o;
    }
    __syncthreads();

    const int lane = tid & 63;
    const int wave = tid >> 6;
    const int wm   = wave >> 1;   // 0..1  (64-row sub-tile)
    const int wn   = wave & 1;    // 0..1  (64-col sub-tile)
    const int t16  = lane & 15;
    const int quad = lane >> 4;

    f32x4 acc[4][4];
    #pragma unroll
    for (int i = 0; i < 4; ++i)
        #pragma unroll
        for (int j = 0; j < 4; ++j)
            acc[i][j] = (f32x4){0.f, 0.f, 0.f, 0.f};

    // W staging thread mapping: 128 n-cols x 8 chunks per 64-K half-stage
    const int n_wst = tid & 127;
    const int ch    = tid >> 7;          // 0/1 -> chunks ch*4+p
    const int ko_st = nt * 128 + n_wst;  // global output-col

    for (int fh = 0; fh < 16; ++fh) {    // f = fh>>1, half h = fh&1
        const int f = fh >> 1;
        const int h = fh & 1;

        if (fh) __syncthreads();         // prev compute done before overwrite
        // ---- stage Wp chunk: k in [f*128 + h*64, +64), cols ko_st
        #pragma unroll
        for (int p = 0; p < 4; ++p) {
            int c  = ch * 4 + p;                  // chunk 0..7 (8 bf16 each)
            int kb = f * 128 + h * 64 + c * 8;    // global fd base
            bf16x8 w8;
            #pragma unroll
            for (int jj = 0; jj < 8; ++jj) {
                float w = Wk[(size_t)(kb + jj) * 256 + ko_st] * filt[kb + jj];
                w8[jj] = f2bf(w);
            }
            int pos = (c ^ n_wst) & 7;            // XOR swizzle
            *reinterpret_cast<bf16x8*>(&sW[n_wst * 64 + pos * 8]) = w8;
        }
        __syncthreads();

        // ---- compute: 2 k-steps of 32, 16 MFMAs each
        #pragma unroll
        for (int s = 0; s < 2; ++s) {
            bf16x8 a[4], b[4];
            #pragma unroll
            for (int i = 0; i < 4; ++i) {
                int row = wm * 64 + i * 16 + t16 + f;      // slab row m+f
                int d   = h * 64 + s * 32 + quad * 8;      // d within row
                a[i] = *reinterpret_cast<const bf16x8*>(&sA[row * 136 + d]);
            }
            #pragma unroll
            for (int j = 0; j < 4; ++j) {
                int n   = wn * 64 + j * 16 + t16;
                int c   = s * 4 + quad;                    // chunk 0..7
                int pos = (c ^ n) & 7;
                b[j] = *reinterpret_cast<const bf16x8*>(&sW[n * 64 + pos * 8]);
            }
            #pragma unroll
            for (int i = 0; i < 4; ++i)
                #pragma unroll
                for (int j = 0; j < 4; ++j)
                    acc[i][j] = __builtin_amdgcn_mfma_f32_16x16x32_bf16(
                        a[i], b[j], acc[i][j], 0, 0, 0);
        }
    }

    // ---- epilogue: bias + relu, C/D layout col=lane&15, row=quad*4+reg
    #pragma unroll
    for (int j = 0; j < 4; ++j) {
        int n_glob = nt * 128 + wn * 64 + j * 16 + t16;
        float bias = bk[n_glob];
        #pragma unroll
        for (int i = 0; i < 4; ++i) {
            #pragma unroll
            for (int r = 0; r < 4; ++r) {
                int m = wm * 64 + i * 16 + quad * 4 + r;
                int l = l0 + m;
                if (l < NWIN) {
                    float v = acc[i][j][r] + bias;
                    out[((size_t)batch * NWIN + l) * 256 + n_glob] =
                        v > 0.f ? v : 0.f;
                }
            }
        }
    }
}

extern "C" void kernel_launch(void* const* d_in, const int* in_sizes, int n_in,
                              void* d_out, int out_size, void* d_ws, size_t ws_size,
                              hipStream_t stream) {
    const float* ub   = (const float*)d_in[0];  // (32,2048,128) fp32
    const float* filt = (const float*)d_in[1];  // (8,128) fp32
    const float* Wk   = (const float*)d_in[2];  // (1024,256) fp32
    const float* bk   = (const float*)d_in[3];  // (256,) fp32
    float* out = (float*)d_out;                 // (32,2040,256) fp32

    dim3 grid(32 * MT * 2), block(256);
    hipLaunchKernelGGL(cnn_enc_kernel, grid, block, 0, stream,
                       ub, filt, Wk, bk, out);
}

// Round 2
// 192.371 us; speedup vs baseline: 1.3329x; 1.3329x over previous
//
#include <hip/hip_runtime.h>

// CNN encoder as implicit-im2col GEMM:
//   A(M=32*2040, K=1024) x Wp(K=1024, N=256), Wp[fd][k] = filt[fd]*W_k[fd][k]
//   out = relu(A*Wp + b_k)
// Round 2: Wp^T precomputed to bf16 in d_ws by a prep kernel; main K-loop is
// barrier-free (A slab in LDS staged once; B frags streamed from L2).

#define L_SZ   2048
#define NWIN   2040   // L - F (reference uses L - F)
#define BM     128
#define MT     16

typedef __attribute__((ext_vector_type(8))) short bf16x8;
typedef __attribute__((ext_vector_type(4))) short bf16x4;
typedef __attribute__((ext_vector_type(4))) float f32x4;

static __device__ __forceinline__ short f2bf(float f) {
    union { float f; unsigned u; } v; v.f = f;
    unsigned r = v.u + 0x7FFFu + ((v.u >> 16) & 1u);
    return (short)(r >> 16);
}

// ---- prep: Wp^T[n][k] = bf16(Wk[k][n] * filt[k]),  n<256, k<1024
__global__ __launch_bounds__(256) void prep_w_kernel(
    const float* __restrict__ Wk, const float* __restrict__ filt,
    short* __restrict__ wp)
{
    int g  = blockIdx.x * 256 + threadIdx.x;  // 32768 threads
    int n  = g & 255;                          // lane-contiguous -> coalesced Wk reads
    int kb = (g >> 8) << 3;                    // k base, 0..1016
    bf16x8 o;
    #pragma unroll
    for (int jj = 0; jj < 8; ++jj)
        o[jj] = f2bf(Wk[(size_t)(kb + jj) * 256 + n] * filt[kb + jj]);
    *reinterpret_cast<bf16x8*>(&wp[(size_t)n * 1024 + kb]) = o;
}

__global__ __launch_bounds__(256) void cnn_enc_kernel(
    const float* __restrict__ ub, const short* __restrict__ wp,
    const float* __restrict__ bk, float* __restrict__ out)
{
    // A slab: 135 rows x 128 d, bf16, row stride 136 (quad a-frag reads 2-way = free)
    __shared__ short sA[135 * 136];

    const int tid   = threadIdx.x;
    const int bid   = blockIdx.x;
    const int nt    = bid & 1;          // N-tile (0/1)
    const int mt    = (bid >> 1) & 15;  // M-tile
    const int batch = bid >> 5;         // 0..31
    const int l0    = mt * BM;

    // ---- stage A slab once (clamped rows feed only masked-out outputs)
    for (int idx = tid; idx < 135 * 32; idx += 256) {
        int r  = idx >> 5;
        int dc = idx & 31;
        int rg = l0 + r; if (rg > L_SZ - 1) rg = L_SZ - 1;
        const float4 v = *reinterpret_cast<const float4*>(
            ub + (((size_t)batch * L_SZ + rg) << 7) + (dc << 2));
        bf16x4 o;
        o.x = f2bf(v.x); o.y = f2bf(v.y); o.z = f2bf(v.z); o.w = f2bf(v.w);
        *reinterpret_cast<bf16x4*>(&sA[r * 136 + (dc << 2)]) = o;
    }
    __syncthreads();   // the ONLY barrier

    const int lane = tid & 63;
    const int wave = tid >> 6;
    const int wm   = wave >> 1;   // 0..1
    const int wn   = wave & 1;    // 0..1
    const int t16  = lane & 15;
    const int quad = lane >> 4;

    f32x4 acc[4][4];
    #pragma unroll
    for (int i = 0; i < 4; ++i)
        #pragma unroll
        for (int j = 0; j < 4; ++j)
            acc[i][j] = (f32x4){0.f, 0.f, 0.f, 0.f};

    // per-lane bases
    int aoff[4];                               // sA offset (shorts), + f*136 + s*32
    #pragma unroll
    for (int i = 0; i < 4; ++i)
        aoff[i] = (wm * 64 + i * 16 + t16) * 136 + quad * 8;
    const short* bptr[4];                      // wp row base + quad*8, + f*128 + s*32
    #pragma unroll
    for (int j = 0; j < 4; ++j)
        bptr[j] = wp + (size_t)(nt * 128 + wn * 64 + j * 16 + t16) * 1024 + quad * 8;

    // ---- barrier-free K loop: 32 steps of K=32, B prefetched 1 step ahead
    bf16x8 bcur[4], bnxt[4], afr[4];
    #pragma unroll
    for (int j = 0; j < 4; ++j)
        bcur[j] = *reinterpret_cast<const bf16x8*>(bptr[j]);

    #pragma unroll
    for (int step = 0; step < 32; ++step) {
        const int f = step >> 2, s = step & 3;
        if (step < 31) {
            const int koff = (step + 1 >> 2) * 128 + ((step + 1) & 3) * 32;
            #pragma unroll
            for (int j = 0; j < 4; ++j)
                bnxt[j] = *reinterpret_cast<const bf16x8*>(bptr[j] + koff);
        }
        #pragma unroll
        for (int i = 0; i < 4; ++i)
            afr[i] = *reinterpret_cast<const bf16x8*>(
                &sA[aoff[i] + f * 136 + s * 32]);
        #pragma unroll
        for (int i = 0; i < 4; ++i)
            #pragma unroll
            for (int j = 0; j < 4; ++j)
                acc[i][j] = __builtin_amdgcn_mfma_f32_16x16x32_bf16(
                    afr[i], bcur[j], acc[i][j], 0, 0, 0);
        #pragma unroll
        for (int j = 0; j < 4; ++j) bcur[j] = bnxt[j];
    }

    // ---- epilogue: bias + relu; C/D: col=lane&15, row=quad*4+reg
    #pragma unroll
    for (int j = 0; j < 4; ++j) {
        int n_glob = nt * 128 + wn * 64 + j * 16 + t16;
        float bias = bk[n_glob];
        #pragma unroll
        for (int i = 0; i < 4; ++i) {
            #pragma unroll
            for (int r = 0; r < 4; ++r) {
                int l = l0 + wm * 64 + i * 16 + quad * 4 + r;
                if (l < NWIN) {
                    float v = acc[i][j][r] + bias;
                    out[((size_t)batch * NWIN + l) * 256 + n_glob] =
                        v > 0.f ? v : 0.f;
                }
            }
        }
    }
}

extern "C" void kernel_launch(void* const* d_in, const int* in_sizes, int n_in,
                              void* d_out, int out_size, void* d_ws, size_t ws_size,
                              hipStream_t stream) {
    const float* ub   = (const float*)d_in[0];  // (32,2048,128) fp32
    const float* filt = (const float*)d_in[1];  // (8,128) fp32
    const float* Wk   = (const float*)d_in[2];  // (1024,256) fp32
    const float* bk   = (const float*)d_in[3];  // (256,) fp32
    float* out = (float*)d_out;                 // (32,2040,256) fp32
    short* wp  = (short*)d_ws;                  // 256*1024 bf16 = 512 KB

    hipLaunchKernelGGL(prep_w_kernel, dim3(128), dim3(256), 0, stream,
                       Wk, filt, wp);
    hipLaunchKernelGGL(cnn_enc_kernel, dim3(32 * MT * 2), dim3(256), 0, stream,
                       ub, wp, bk, out);
}